// Round 3
// baseline (1236.247 us; speedup 1.0000x reference)
//
#include <hip/hip_runtime.h>
#include <hip/hip_bf16.h>
#include <math.h>

// Problem constants
#define Bb   32
#define Ss   512
#define Hh   768
#define Dd   64
#define ND   128          // 2*D
#define Mrows (Bb*Ss)     // 16384
#define BIGF 1.0e12f

typedef __attribute__((ext_vector_type(8))) short short8;   // 8 bf16
typedef __attribute__((ext_vector_type(4))) float floatx4;  // 4 f32 acc

__device__ __forceinline__ short f2bf(float x) {
    unsigned u = __builtin_bit_cast(unsigned, x);
    u = (u + 0x7FFF + ((u >> 16) & 1)) >> 16;   // RNE
    return (short)u;
}

// ---------------------------------------------------------------------------
// Kernel 0: w (768,128) f32 -> wT (128,768) bf16.
// ---------------------------------------------------------------------------
__global__ __launch_bounds__(256) void wcvt_kernel(
    const float* __restrict__ w, short* __restrict__ wT)
{
    int idx = blockIdx.x * 256 + threadIdx.x;   // 98304 total
    int k = idx >> 7;          // 0..767
    int n = idx & 127;         // 0..127
    wT[n * Hh + k] = f2bf(w[idx]);
}

// ---------------------------------------------------------------------------
// Kernel 1: MFMA bf16 projection + bias + RoPE -> q/k (f32).
// Grid 512 blocks x 256 thr. Wave tile: 16 rows x 64 cols (half = q or k).
// LDS-free: A-frags from fp32 hidden (converted in-reg), B-frags from wT.
// ---------------------------------------------------------------------------
__global__ __launch_bounds__(256) void proj_rope_kernel(
    const float* __restrict__ hidden,   // (M, H) f32
    const short* __restrict__ wT,       // (128, 768) bf16
    const float* __restrict__ bias,     // (128,) f32
    float* __restrict__ qout,           // (M, 64)
    float* __restrict__ kout)           // (M, 64)
{
    const int tid   = threadIdx.x;
    const int w     = tid >> 6;          // wave 0..3
    const int lane  = tid & 63;
    const int quad  = lane >> 4;         // 0..3
    const int l15   = lane & 15;
    const int h     = w & 1;             // 0 = q cols, 1 = k cols
    const int mrow0 = blockIdx.x * 32 + (w >> 1) * 16;

    // A pointer: row (mrow0+l15), k offset quad*8
    const float* ap = hidden + (size_t)(mrow0 + l15) * Hh + quad * 8;
    // B pointers: 4 n-tiles
    const short* bp[4];
    #pragma unroll
    for (int t = 0; t < 4; ++t)
        bp[t] = wT + (size_t)(h * 64 + t * 16 + l15) * Hh + quad * 8;

    floatx4 acc[4] = {{0.f,0.f,0.f,0.f},{0.f,0.f,0.f,0.f},
                      {0.f,0.f,0.f,0.f},{0.f,0.f,0.f,0.f}};

    // double-buffered register pipeline over 24 K-chunks of 32
    float4 A0[2], A1[2];
    short8 Bf[2][4];

    A0[0] = *(const float4*)(ap);
    A1[0] = *(const float4*)(ap + 4);
    #pragma unroll
    for (int t = 0; t < 4; ++t) Bf[0][t] = *(const short8*)(bp[t]);

    #pragma unroll 1
    for (int c = 0; c < 24; ++c) {
        const int cur = c & 1, nxt = cur ^ 1;
        if (c < 23) {
            const int k1 = (c + 1) * 32;
            A0[nxt] = *(const float4*)(ap + k1);
            A1[nxt] = *(const float4*)(ap + k1 + 4);
            #pragma unroll
            for (int t = 0; t < 4; ++t)
                Bf[nxt][t] = *(const short8*)(bp[t] + k1);
        }
        short8 av;
        av[0] = f2bf(A0[cur].x); av[1] = f2bf(A0[cur].y);
        av[2] = f2bf(A0[cur].z); av[3] = f2bf(A0[cur].w);
        av[4] = f2bf(A1[cur].x); av[5] = f2bf(A1[cur].y);
        av[6] = f2bf(A1[cur].z); av[7] = f2bf(A1[cur].w);
        #pragma unroll
        for (int t = 0; t < 4; ++t)
            acc[t] = __builtin_amdgcn_mfma_f32_16x16x32_bf16(
                         av, Bf[cur][t], acc[t], 0, 0, 0);
    }

    // ---- Epilogue: bias + RoPE. C/D layout: col=l15, row=quad*4+reg.
    float* dst = h ? kout : qout;
    const float* bptr = bias + h * 64;
    const float ln_base = -logf(10000.0f) / 32.0f;

    #pragma unroll
    for (int t = 0; t < 4; ++t) {
        const int d = t * 16 + l15;          // 0..63 within q/k
        const float bz = bptr[d];
        const float invf = expf(ln_base * (float)(d >> 1));
        #pragma unroll
        for (int reg = 0; reg < 4; ++reg) {
            const int grow = mrow0 + quad * 4 + reg;
            const int spos = grow & (Ss - 1);
            float x  = acc[t][reg] + bz;
            float xo = __shfl_xor(x, 1);
            float sn, cs;
            sincosf((float)spos * invf, &sn, &cs);
            float o = (d & 1) ? (x * cs + xo * sn) : (x * cs - xo * sn);
            dst[(size_t)grow * Dd + d] = o;
        }
    }
}

// ---------------------------------------------------------------------------
// Kernel 2: per-slice logits + masks + dual logsumexp.
// Grid: 32 batches x 16 slices of 32 rows. 512 threads; thread n owns k-col n
// in registers. q slice in LDS (broadcast reads). 4 rows per reduction round.
// ---------------------------------------------------------------------------
__global__ __launch_bounds__(512) void span_loss_kernel(
    const float* __restrict__ q,        // (M, 64)
    const float* __restrict__ k,        // (M, 64)
    const float* __restrict__ mask,     // (B, S)
    const int*   __restrict__ span,     // (B, S, S)
    double* __restrict__ rowsum)        // (M,)
{
    const int b    = blockIdx.x >> 4;
    const int m0   = (blockIdx.x & 15) * 32;  // first row (within batch)
    const int tid  = threadIdx.x;             // 0..511 == column n
    const int n    = tid;
    const int wave = tid >> 6;
    const int lane = tid & 63;

    __shared__ __align__(16) float qs[32][64];   // 8 KB
    __shared__ float wmax[8][8];                  // [value][wave]
    __shared__ float wsum[8][8];

    // k column -> registers (256 B contiguous per thread)
    float4 kreg[16];
    {
        const float4* krow = (const float4*)(k + (size_t)(b * Ss + n) * Dd);
        #pragma unroll
        for (int i = 0; i < 16; ++i) kreg[i] = krow[i];
    }
    const float pad = mask[b * Ss + n];

    // stage q slice (32 rows) coalesced
    {
        const float4* qsrc = (const float4*)(q + (size_t)(b * Ss + m0) * Dd);
        ((float4*)&qs[0][0])[tid] = qsrc[tid];
    }
    __syncthreads();

    const int* sp_base = span + ((size_t)(b * Ss + m0)) * Ss + n;

    int sp[4];
    #pragma unroll
    for (int j = 0; j < 4; ++j) sp[j] = sp_base[(size_t)j * Ss];

    #pragma unroll 1
    for (int g = 0; g < 8; ++g) {
        const int r0 = g * 4;
        int spn[4];
        if (g < 7) {
            #pragma unroll
            for (int j = 0; j < 4; ++j)
                spn[j] = sp_base[(size_t)(r0 + 4 + j) * Ss];
        }

        // ---- dots for 4 rows
        float dt[4] = {0.f, 0.f, 0.f, 0.f};
        const float4* q0 = (const float4*)&qs[r0][0];
        #pragma unroll
        for (int d4 = 0; d4 < 16; ++d4) {
            float4 kv = kreg[d4];
            #pragma unroll
            for (int j = 0; j < 4; ++j) {
                float4 qv = q0[j * 16 + d4];      // broadcast
                dt[j] = fmaf(qv.x, kv.x, dt[j]);
                dt[j] = fmaf(qv.y, kv.y, dt[j]);
                dt[j] = fmaf(qv.z, kv.z, dt[j]);
                dt[j] = fmaf(qv.w, kv.w, dt[j]);
            }
        }

        // ---- elementwise epilogue -> vneg/vpos per row
        float vneg[4], vpos[4];
        #pragma unroll
        for (int j = 0; j < 4; ++j) {
            int m = m0 + r0 + j;
            float logit = dt[j] * pad - (1.0f - pad) * BIGF;
            if (n < m) logit -= BIGF;
            logit *= 0.125f;
            float ft = (float)sp[j];
            float yp = (1.0f - 2.0f * ft) * logit;
            vneg[j] = yp - ft * BIGF;
            vpos[j] = yp - (1.0f - ft) * BIGF;
        }

        // ---- block max (zero entry folded via init-with-0)
        float mx[8];
        #pragma unroll
        for (int j = 0; j < 4; ++j) {
            mx[j]     = fmaxf(vneg[j], 0.0f);
            mx[4 + j] = fmaxf(vpos[j], 0.0f);
        }
        #pragma unroll
        for (int off = 32; off > 0; off >>= 1) {
            #pragma unroll
            for (int v = 0; v < 8; ++v)
                mx[v] = fmaxf(mx[v], __shfl_xor(mx[v], off));
        }
        if (lane == 0) {
            #pragma unroll
            for (int v = 0; v < 8; ++v) wmax[v][wave] = mx[v];
        }
        __syncthreads();
        float bm[8];
        #pragma unroll
        for (int v = 0; v < 8; ++v) {
            float t = wmax[v][0];
            #pragma unroll
            for (int ww = 1; ww < 8; ++ww) t = fmaxf(t, wmax[v][ww]);
            bm[v] = t;
        }

        // ---- block sum of exp
        float sm[8];
        #pragma unroll
        for (int j = 0; j < 4; ++j) {
            sm[j]     = __expf(vneg[j] - bm[j]);
            sm[4 + j] = __expf(vpos[j] - bm[4 + j]);
        }
        #pragma unroll
        for (int off = 32; off > 0; off >>= 1) {
            #pragma unroll
            for (int v = 0; v < 8; ++v)
                sm[v] += __shfl_xor(sm[v], off);
        }
        if (lane == 0) {
            #pragma unroll
            for (int v = 0; v < 8; ++v) wsum[v][wave] = sm[v];
        }
        __syncthreads();

        if (tid < 4) {
            int j = tid;
            float SN = __expf(-bm[j]);
            float SP = __expf(-bm[4 + j]);
            #pragma unroll
            for (int ww = 0; ww < 8; ++ww) {
                SN += wsum[j][ww];
                SP += wsum[4 + j][ww];
            }
            float lse = (bm[j] + logf(SN)) + (bm[4 + j] + logf(SP));
            rowsum[(size_t)(b * Ss + m0 + r0 + j)] = (double)lse;
        }

        #pragma unroll
        for (int j = 0; j < 4; ++j) sp[j] = spn[j];
    }
}

// ---------------------------------------------------------------------------
// Kernel 3: fp64 mean over 16384 row sums -> fp32 scalar.
// ---------------------------------------------------------------------------
__global__ __launch_bounds__(1024) void final_reduce_kernel(
    const double* __restrict__ rowsum, float* __restrict__ out)
{
    __shared__ double sh[1024];
    const int tid = threadIdx.x;
    double s = 0.0;
    #pragma unroll
    for (int i = 0; i < 16; ++i) s += rowsum[tid + i * 1024];
    sh[tid] = s;
    __syncthreads();
    for (int off = 512; off > 0; off >>= 1) {
        if (tid < off) sh[tid] += sh[tid + off];
        __syncthreads();
    }
    if (tid == 0) out[0] = (float)(sh[0] / (double)Mrows);
}

// ---------------------------------------------------------------------------
extern "C" void kernel_launch(void* const* d_in, const int* in_sizes, int n_in,
                              void* d_out, int out_size, void* d_ws, size_t ws_size,
                              hipStream_t stream)
{
    const float* hidden = (const float*)d_in[0];   // (B,S,H)
    const float* mask   = (const float*)d_in[1];   // (B,S)
    const int*   span   = (const int*)  d_in[2];   // (B,S,S)
    const float* w      = (const float*)d_in[3];   // (H, 2D)
    const float* bias   = (const float*)d_in[4];   // (2D,)
    float* out = (float*)d_out;

    // ws layout:
    //  [rowsum: 16384 f64 = 131072 B]
    //  [wT:     98304 bf16 = 196608 B]
    //  [q:      16384*64 f32 = 4 MB]
    //  [k:      16384*64 f32 = 4 MB]
    double* rowsum = (double*)d_ws;
    short*  wT     = (short*)((char*)d_ws + 131072);
    float*  qbuf   = (float*)((char*)d_ws + 131072 + 196608);
    float*  kbuf   = qbuf + (size_t)Mrows * Dd;

    wcvt_kernel<<<Hh * ND / 256, 256, 0, stream>>>(w, wT);
    proj_rope_kernel<<<Mrows / 32, 256, 0, stream>>>(hidden, wT, bias, qbuf, kbuf);
    span_loss_kernel<<<Bb * 16, 512, 0, stream>>>(qbuf, kbuf, mask, span, rowsum);
    final_reduce_kernel<<<1, 1024, 0, stream>>>(rowsum, out);
}

// Round 4
// 158.461 us; speedup vs baseline: 7.8016x; 7.8016x over previous
//
#include <hip/hip_runtime.h>
#include <hip/hip_bf16.h>
#include <math.h>

// Problem constants
#define Bb   32
#define Ss   512
#define Hh   768
#define Dd   64
#define ND   128          // 2*D
#define Mrows (Bb*Ss)     // 16384
#define BIGF 1.0e12f

typedef __attribute__((ext_vector_type(8))) short short8;   // 8 bf16
typedef __attribute__((ext_vector_type(4))) float floatx4;  // 4 f32 acc

__device__ __forceinline__ short f2bf(float x) {
    unsigned u = __builtin_bit_cast(unsigned, x);
    u = (u + 0x7FFF + ((u >> 16) & 1)) >> 16;   // RNE
    return (short)u;
}

// ---------------------------------------------------------------------------
// Kernel 0: w (768,128) f32 -> wT (128,768) bf16; RoPE sin/cos table.
// ---------------------------------------------------------------------------
__global__ __launch_bounds__(256) void prep_kernel(
    const float* __restrict__ w, short* __restrict__ wT,
    float2* __restrict__ rt)                   // rt[spos*32 + i] = (sin, cos)
{
    int idx = blockIdx.x * 256 + threadIdx.x;  // 98304 total
    int k = idx >> 7;          // 0..767
    int n = idx & 127;         // 0..127
    wT[n * Hh + k] = f2bf(w[idx]);
    if (idx < Ss * 32) {
        int spos = idx >> 5;
        int i    = idx & 31;
        float ln_base = -logf(10000.0f) / 32.0f;
        float invf = expf(ln_base * (float)i);
        float sn, cs;
        sincosf((float)spos * invf, &sn, &cs);
        rt[idx] = make_float2(sn, cs);
    }
}

// ---------------------------------------------------------------------------
// Kernel 1: MFMA bf16 projection + bias + RoPE -> q/k (bf16).
// Grid 512 x 256. Wave tile 16 rows x 64 cols (h: 0=q, 1=k). LDS-free.
// Double buffer with COMPILE-TIME indices (R3 post-mortem: runtime indices
// demoted the buffers to scratch -> 12x regression).
// ---------------------------------------------------------------------------
__global__ __launch_bounds__(256) void proj_rope_kernel(
    const float*  __restrict__ hidden,   // (M, H) f32
    const short*  __restrict__ wT,       // (128, 768) bf16
    const float*  __restrict__ bias,     // (128,) f32
    const float2* __restrict__ rt,       // (512, 32) sin/cos
    short* __restrict__ qbf,             // (M, 64) bf16
    short* __restrict__ kbf)             // (M, 64) bf16
{
    const int tid   = threadIdx.x;
    const int w     = tid >> 6;          // wave 0..3
    const int lane  = tid & 63;
    const int quad  = lane >> 4;
    const int l15   = lane & 15;
    const int h     = w & 1;             // 0 = q cols, 1 = k cols
    const int mrow0 = blockIdx.x * 32 + (w >> 1) * 16;

    const float* ap  = hidden + (size_t)(mrow0 + l15) * Hh + quad * 8;
    const short* bp0 = wT + (size_t)(h * 64 + l15) * Hh + quad * 8;

    floatx4 acc[4] = {{0.f,0.f,0.f,0.f},{0.f,0.f,0.f,0.f},
                      {0.f,0.f,0.f,0.f},{0.f,0.f,0.f,0.f}};

    float4 A0[2], A1[2];
    short8 Bf[2][4];

#define PLOAD(buf, kofs) do {                                   \
    A0[buf] = *(const float4*)(ap + (kofs));                    \
    A1[buf] = *(const float4*)(ap + (kofs) + 4);                \
    Bf[buf][0] = *(const short8*)(bp0 + (kofs));                \
    Bf[buf][1] = *(const short8*)(bp0 + 16 * Hh + (kofs));      \
    Bf[buf][2] = *(const short8*)(bp0 + 32 * Hh + (kofs));      \
    Bf[buf][3] = *(const short8*)(bp0 + 48 * Hh + (kofs));      \
} while (0)

#define PCOMP(buf) do {                                         \
    short8 av;                                                  \
    av[0] = f2bf(A0[buf].x); av[1] = f2bf(A0[buf].y);           \
    av[2] = f2bf(A0[buf].z); av[3] = f2bf(A0[buf].w);           \
    av[4] = f2bf(A1[buf].x); av[5] = f2bf(A1[buf].y);           \
    av[6] = f2bf(A1[buf].z); av[7] = f2bf(A1[buf].w);           \
    acc[0] = __builtin_amdgcn_mfma_f32_16x16x32_bf16(av, Bf[buf][0], acc[0], 0, 0, 0); \
    acc[1] = __builtin_amdgcn_mfma_f32_16x16x32_bf16(av, Bf[buf][1], acc[1], 0, 0, 0); \
    acc[2] = __builtin_amdgcn_mfma_f32_16x16x32_bf16(av, Bf[buf][2], acc[2], 0, 0, 0); \
    acc[3] = __builtin_amdgcn_mfma_f32_16x16x32_bf16(av, Bf[buf][3], acc[3], 0, 0, 0); \
} while (0)

    PLOAD(0, 0);
    #pragma unroll
    for (int cc = 0; cc < 12; ++cc) {
        if (2 * cc + 1 < 24) PLOAD(1, (2 * cc + 1) * 32);
        PCOMP(0);
        if (2 * cc + 2 < 24) PLOAD(0, (2 * cc + 2) * 32);
        PCOMP(1);
    }
#undef PLOAD
#undef PCOMP

    // ---- Epilogue: bias + RoPE (table) -> bf16 store.
    short* dst = h ? kbf : qbf;
    const float* bptr = bias + h * 64;

    #pragma unroll
    for (int t = 0; t < 4; ++t) {
        const int d  = t * 16 + l15;               // 0..63 within q/k half
        const float bz = bptr[d];
        const float2* rtp = rt + (d >> 1);
        #pragma unroll
        for (int reg = 0; reg < 4; ++reg) {
            const int grow = mrow0 + quad * 4 + reg;
            const int spos = grow & (Ss - 1);
            float2 sc = rtp[spos * 32];
            float x  = acc[t][reg] + bz;
            float xo = __shfl_xor(x, 1);
            float o  = (d & 1) ? (x * sc.y + xo * sc.x)
                               : (x * sc.y - xo * sc.x);
            dst[(size_t)grow * Dd + d] = f2bf(o);
        }
    }
}

// ---------------------------------------------------------------------------
// Kernel 2: MFMA QK^T + masks + dual logsumexp.
// Grid: 32 batches x 16 slices of 32 rows; 512 threads (8 waves).
// Wave (rh = w&1, cg = w>>2? no: cg = w>>1): rows rh*16.., cols cg*128..
// C layout: col = l15 (within 16-tile), row = quad*4 + reg.
// ---------------------------------------------------------------------------
__global__ __launch_bounds__(512) void span_loss_kernel(
    const short* __restrict__ qbf,      // (M, 64) bf16
    const short* __restrict__ kbf,      // (M, 64) bf16
    const float* __restrict__ mask,     // (B, S)
    const int*   __restrict__ span,     // (B, S, S)
    double* __restrict__ rowsum)        // (M,)
{
    const int b    = blockIdx.x >> 4;
    const int m0   = (blockIdx.x & 15) * 32;
    const int tid  = threadIdx.x;
    const int w    = tid >> 6;
    const int lane = tid & 63;
    const int quad = lane >> 4;
    const int l15  = lane & 15;
    const int rh   = w & 1;              // row half (16 rows)
    const int cg   = w >> 1;             // col group (128 cols)
    const int rbase = m0 + rh * 16;      // + quad*4 + reg   (within batch)
    const int cbase = cg * 128;          // + t*16 + l15

    __shared__ float part[2][4][32];     // [neg/pos][colgroup][row]
    __shared__ float bred[2][32];        // block max per row

    // ---- A frags (Q): rows rbase + l15
    const short* qp = qbf + (size_t)(b * Ss + rbase + l15) * Dd + quad * 8;
    short8 a0 = *(const short8*)(qp);
    short8 a1 = *(const short8*)(qp + 32);

    floatx4 acc[8];
    #pragma unroll
    for (int t = 0; t < 8; ++t) acc[t] = (floatx4){0.f, 0.f, 0.f, 0.f};

    // ---- B frags (K): cols cbase + t*16 + l15; two K-chunks sequentially.
    const short* kp = kbf + (size_t)(b * Ss + cbase + l15) * Dd + quad * 8;
    #pragma unroll
    for (int t = 0; t < 8; ++t) {
        short8 bv = *(const short8*)(kp + (size_t)t * 16 * Dd);
        acc[t] = __builtin_amdgcn_mfma_f32_16x16x32_bf16(a0, bv, acc[t], 0, 0, 0);
    }
    #pragma unroll
    for (int t = 0; t < 8; ++t) {
        short8 bv = *(const short8*)(kp + (size_t)t * 16 * Dd + 32);
        acc[t] = __builtin_amdgcn_mfma_f32_16x16x32_bf16(a1, bv, acc[t], 0, 0, 0);
    }

    // ---- Epilogue: transform dots -> yp in place, pack span bits.
    unsigned spb = 0;
    #pragma unroll
    for (int t = 0; t < 8; ++t) {
        const int n = cbase + t * 16 + l15;
        const float pd = mask[b * Ss + n];
        #pragma unroll
        for (int reg = 0; reg < 4; ++reg) {
            const int m = rbase + quad * 4 + reg;
            const int sv = span[((size_t)(b * Ss + m)) * Ss + n];
            float logit = acc[t][reg] * pd - (1.0f - pd) * BIGF;
            if (n < m) logit -= BIGF;
            logit *= 0.125f;
            float ft = (float)sv;
            acc[t][reg] = (1.0f - 2.0f * ft) * logit;   // yp
            spb |= (unsigned)(sv != 0) << (t * 4 + reg);
        }
    }

    // ---- Pass 1: max (zero entry folded via init 0).
    float mxn[4] = {0.f, 0.f, 0.f, 0.f};
    float mxp[4] = {0.f, 0.f, 0.f, 0.f};
    #pragma unroll
    for (int t = 0; t < 8; ++t) {
        #pragma unroll
        for (int reg = 0; reg < 4; ++reg) {
            float ft = (float)((spb >> (t * 4 + reg)) & 1u);
            float yp = acc[t][reg];
            mxn[reg] = fmaxf(mxn[reg], yp - ft * BIGF);
            mxp[reg] = fmaxf(mxp[reg], yp - (1.0f - ft) * BIGF);
        }
    }
    #pragma unroll
    for (int off = 1; off < 16; off <<= 1) {
        #pragma unroll
        for (int reg = 0; reg < 4; ++reg) {
            mxn[reg] = fmaxf(mxn[reg], __shfl_xor(mxn[reg], off));
            mxp[reg] = fmaxf(mxp[reg], __shfl_xor(mxp[reg], off));
        }
    }
    if (l15 == 0) {
        #pragma unroll
        for (int reg = 0; reg < 4; ++reg) {
            part[0][cg][rh * 16 + quad * 4 + reg] = mxn[reg];
            part[1][cg][rh * 16 + quad * 4 + reg] = mxp[reg];
        }
    }
    __syncthreads();
    if (tid < 64) {
        int np = tid >> 5, r = tid & 31;
        float mv = fmaxf(fmaxf(part[np][0][r], part[np][1][r]),
                         fmaxf(part[np][2][r], part[np][3][r]));
        bred[np][r] = mv;
    }
    __syncthreads();

    // ---- Pass 2: sum of exp(v - max).
    float bmn[4], bmp[4];
    #pragma unroll
    for (int reg = 0; reg < 4; ++reg) {
        bmn[reg] = bred[0][rh * 16 + quad * 4 + reg];
        bmp[reg] = bred[1][rh * 16 + quad * 4 + reg];
    }
    float smn[4] = {0.f, 0.f, 0.f, 0.f};
    float smp[4] = {0.f, 0.f, 0.f, 0.f};
    #pragma unroll
    for (int t = 0; t < 8; ++t) {
        #pragma unroll
        for (int reg = 0; reg < 4; ++reg) {
            float ft = (float)((spb >> (t * 4 + reg)) & 1u);
            float yp = acc[t][reg];
            smn[reg] += __expf(yp - ft * BIGF - bmn[reg]);
            smp[reg] += __expf(yp - (1.0f - ft) * BIGF - bmp[reg]);
        }
    }
    #pragma unroll
    for (int off = 1; off < 16; off <<= 1) {
        #pragma unroll
        for (int reg = 0; reg < 4; ++reg) {
            smn[reg] += __shfl_xor(smn[reg], off);
            smp[reg] += __shfl_xor(smp[reg], off);
        }
    }
    if (l15 == 0) {
        #pragma unroll
        for (int reg = 0; reg < 4; ++reg) {
            part[0][cg][rh * 16 + quad * 4 + reg] = smn[reg];
            part[1][cg][rh * 16 + quad * 4 + reg] = smp[reg];
        }
    }
    __syncthreads();

    if (tid < 32) {
        int r = tid;
        float SN = __expf(-bred[0][r])
                 + part[0][0][r] + part[0][1][r] + part[0][2][r] + part[0][3][r];
        float SP = __expf(-bred[1][r])
                 + part[1][0][r] + part[1][1][r] + part[1][2][r] + part[1][3][r];
        float lse = (bred[0][r] + logf(SN)) + (bred[1][r] + logf(SP));
        rowsum[(size_t)(b * Ss + m0 + r)] = (double)lse;
    }
}

// ---------------------------------------------------------------------------
// Kernel 3: fp64 mean over 16384 row sums -> fp32 scalar.
// ---------------------------------------------------------------------------
__global__ __launch_bounds__(1024) void final_reduce_kernel(
    const double* __restrict__ rowsum, float* __restrict__ out)
{
    __shared__ double sh[1024];
    const int tid = threadIdx.x;
    double s = 0.0;
    #pragma unroll
    for (int i = 0; i < 16; ++i) s += rowsum[tid + i * 1024];
    sh[tid] = s;
    __syncthreads();
    for (int off = 512; off > 0; off >>= 1) {
        if (tid < off) sh[tid] += sh[tid + off];
        __syncthreads();
    }
    if (tid == 0) out[0] = (float)(sh[0] / (double)Mrows);
}

// ---------------------------------------------------------------------------
extern "C" void kernel_launch(void* const* d_in, const int* in_sizes, int n_in,
                              void* d_out, int out_size, void* d_ws, size_t ws_size,
                              hipStream_t stream)
{
    const float* hidden = (const float*)d_in[0];   // (B,S,H)
    const float* mask   = (const float*)d_in[1];   // (B,S)
    const int*   span   = (const int*)  d_in[2];   // (B,S,S)
    const float* w      = (const float*)d_in[3];   // (H, 2D)
    const float* bias   = (const float*)d_in[4];   // (2D,)
    float* out = (float*)d_out;

    // ws layout:
    //  [rowsum: 16384 f64           = 131072 B]
    //  [wT:     98304 bf16          = 196608 B]
    //  [rt:     16384 float2        = 131072 B]
    //  [qbf:    16384*64 bf16       = 2 MB]
    //  [kbf:    16384*64 bf16       = 2 MB]
    char* p = (char*)d_ws;
    double* rowsum = (double*)p;            p += 131072;
    short*  wT     = (short*)p;             p += 196608;
    float2* rt     = (float2*)p;            p += 131072;
    short*  qbf    = (short*)p;             p += (size_t)Mrows * Dd * 2;
    short*  kbf    = (short*)p;

    prep_kernel<<<Hh * ND / 256, 256, 0, stream>>>(w, wT, rt);
    proj_rope_kernel<<<Mrows / 32, 256, 0, stream>>>(hidden, wT, bias, rt, qbf, kbf);
    span_loss_kernel<<<Bb * 16, 512, 0, stream>>>(qbf, kbf, mask, span, rowsum);
    final_reduce_kernel<<<1, 1024, 0, stream>>>(rowsum, out);
}

// Round 5
// 145.733 us; speedup vs baseline: 8.4830x; 1.0873x over previous
//
#include <hip/hip_runtime.h>
#include <hip/hip_bf16.h>
#include <math.h>

// Problem constants
#define Bb   32
#define Ss   512
#define Hh   768
#define Dd   64
#define ND   128          // 2*D
#define Mrows (Bb*Ss)     // 16384
#define BIGF 1.0e12f

typedef __attribute__((ext_vector_type(8))) short short8;   // 8 bf16
typedef __attribute__((ext_vector_type(4))) float floatx4;  // 4 f32 acc

__device__ __forceinline__ short f2bf(float x) {
    unsigned u = __builtin_bit_cast(unsigned, x);
    u = (u + 0x7FFF + ((u >> 16) & 1)) >> 16;   // RNE
    return (short)u;
}

// ---------------------------------------------------------------------------
// Kernel 0: w (768,128) f32 -> wfrag in MFMA-fragment-major bf16 layout:
//   wfrag[((tt*24 + c)*64 + lane)*8 + j]  (tt = h*4+t)
//   maps to  n = tt*16 + (lane&15),  k = c*32 + (lane>>4)*8 + j
// so a wave's B-frag load for (tt, chunk c) is lane-contiguous (16 B/lane).
// Also builds the RoPE sin/cos table.
// ---------------------------------------------------------------------------
__global__ __launch_bounds__(256) void prep_kernel(
    const float* __restrict__ w, short* __restrict__ wfrag,
    float2* __restrict__ rt)                   // rt[spos*32 + i] = (sin, cos)
{
    int idx = blockIdx.x * 256 + threadIdx.x;  // 98304 total
    int j    = idx & 7;
    int lane = (idx >> 3) & 63;
    int rest = idx >> 9;                       // tt*24 + c
    int c    = rest % 24;
    int tt   = rest / 24;
    int n    = tt * 16 + (lane & 15);
    int k    = c * 32 + (lane >> 4) * 8 + j;
    wfrag[idx] = f2bf(w[k * ND + n]);
    if (idx < Ss * 32) {
        int spos = idx >> 5;
        int i    = idx & 31;
        float ln_base = -logf(10000.0f) / 32.0f;
        float invf = expf(ln_base * (float)i);
        float sn, cs;
        sincosf((float)spos * invf, &sn, &cs);
        rt[idx] = make_float2(sn, cs);
    }
}

// ---------------------------------------------------------------------------
// Kernel 1: MFMA bf16 projection + bias + RoPE -> q/k (bf16).
// Grid 512 x 256. Wave tile 16 rows x 64 cols (h: 0=q, 1=k). LDS-free.
// __launch_bounds__(256,2): R4 post-mortem — default heuristic capped VGPRs
// at ~56 (8-waves/EU target) and demolished the double-buffer pipeline.
// ---------------------------------------------------------------------------
__global__ __launch_bounds__(256, 2) void proj_rope_kernel(
    const float*  __restrict__ hidden,   // (M, H) f32
    const short*  __restrict__ wfrag,    // fragment-major bf16 (see prep)
    const float*  __restrict__ bias,     // (128,) f32
    const float2* __restrict__ rt,       // (512, 32) sin/cos
    short* __restrict__ qbf,             // (M, 64) bf16
    short* __restrict__ kbf)             // (M, 64) bf16
{
    const int tid   = threadIdx.x;
    const int w     = tid >> 6;          // wave 0..3
    const int lane  = tid & 63;
    const int quad  = lane >> 4;
    const int l15   = lane & 15;
    const int h     = w & 1;             // 0 = q cols, 1 = k cols
    const int mrow0 = blockIdx.x * 32 + (w >> 1) * 16;

    const float* ap  = hidden + (size_t)(mrow0 + l15) * Hh + quad * 8;
    const short* bp0 = wfrag + (size_t)(h * 4) * 24 * 512 + lane * 8;

    floatx4 acc[4] = {{0.f,0.f,0.f,0.f},{0.f,0.f,0.f,0.f},
                      {0.f,0.f,0.f,0.f},{0.f,0.f,0.f,0.f}};

    float4 A0[2], A1[2];
    short8 Bf[2][4];

#define PLOAD(buf, c) do {                                        \
    A0[buf] = *(const float4*)(ap + (c) * 32);                    \
    A1[buf] = *(const float4*)(ap + (c) * 32 + 4);                \
    Bf[buf][0] = *(const short8*)(bp0 + 0 * 24 * 512 + (c) * 512);\
    Bf[buf][1] = *(const short8*)(bp0 + 1 * 24 * 512 + (c) * 512);\
    Bf[buf][2] = *(const short8*)(bp0 + 2 * 24 * 512 + (c) * 512);\
    Bf[buf][3] = *(const short8*)(bp0 + 3 * 24 * 512 + (c) * 512);\
} while (0)

#define PCOMP(buf) do {                                         \
    short8 av;                                                  \
    av[0] = f2bf(A0[buf].x); av[1] = f2bf(A0[buf].y);           \
    av[2] = f2bf(A0[buf].z); av[3] = f2bf(A0[buf].w);           \
    av[4] = f2bf(A1[buf].x); av[5] = f2bf(A1[buf].y);           \
    av[6] = f2bf(A1[buf].z); av[7] = f2bf(A1[buf].w);           \
    acc[0] = __builtin_amdgcn_mfma_f32_16x16x32_bf16(av, Bf[buf][0], acc[0], 0, 0, 0); \
    acc[1] = __builtin_amdgcn_mfma_f32_16x16x32_bf16(av, Bf[buf][1], acc[1], 0, 0, 0); \
    acc[2] = __builtin_amdgcn_mfma_f32_16x16x32_bf16(av, Bf[buf][2], acc[2], 0, 0, 0); \
    acc[3] = __builtin_amdgcn_mfma_f32_16x16x32_bf16(av, Bf[buf][3], acc[3], 0, 0, 0); \
} while (0)

    PLOAD(0, 0);
    #pragma unroll
    for (int cc = 0; cc < 12; ++cc) {
        if (2 * cc + 1 < 24) PLOAD(1, 2 * cc + 1);
        PCOMP(0);
        if (2 * cc + 2 < 24) PLOAD(0, 2 * cc + 2);
        PCOMP(1);
    }
#undef PLOAD
#undef PCOMP

    // ---- Epilogue: bias + RoPE (table) -> bf16 store.
    short* dst = h ? kbf : qbf;
    const float* bptr = bias + h * 64;

    #pragma unroll
    for (int t = 0; t < 4; ++t) {
        const int d  = t * 16 + l15;               // 0..63 within q/k half
        const float bz = bptr[d];
        const float2* rtp = rt + (d >> 1);
        #pragma unroll
        for (int reg = 0; reg < 4; ++reg) {
            const int grow = mrow0 + quad * 4 + reg;
            const int spos = grow & (Ss - 1);
            float2 sc = rtp[spos * 32];
            float x  = acc[t][reg] + bz;
            float xo = __shfl_xor(x, 1);
            float o  = (d & 1) ? (x * sc.y + xo * sc.x)
                               : (x * sc.y - xo * sc.x);
            dst[(size_t)grow * Dd + d] = f2bf(o);
        }
    }
}

// ---------------------------------------------------------------------------
// Kernel 2: MFMA QK^T + masks + dual logsumexp.
// Grid: 32 batches x 16 slices of 32 rows; 512 threads (8 waves).
// span/mask loads hoisted BEFORE the MFMAs so HBM latency overlaps compute.
// ---------------------------------------------------------------------------
__global__ __launch_bounds__(512, 4) void span_loss_kernel(
    const short* __restrict__ qbf,      // (M, 64) bf16
    const short* __restrict__ kbf,      // (M, 64) bf16
    const float* __restrict__ mask,     // (B, S)
    const int*   __restrict__ span,     // (B, S, S)
    double* __restrict__ rowsum)        // (M,)
{
    const int b    = blockIdx.x >> 4;
    const int m0   = (blockIdx.x & 15) * 32;
    const int tid  = threadIdx.x;
    const int w    = tid >> 6;
    const int lane = tid & 63;
    const int quad = lane >> 4;
    const int l15  = lane & 15;
    const int rh   = w & 1;              // row half (16 rows)
    const int cg   = w >> 1;             // col group (128 cols)
    const int rbase = m0 + rh * 16;      // + quad*4 + reg   (within batch)
    const int cbase = cg * 128;          // + t*16 + l15

    __shared__ float part[2][4][32];     // [neg/pos][colgroup][row]
    __shared__ float bred[2][32];        // block max/… per row

    // ---- hoisted span + mask loads (independent of MFMA results)
    int spv[8][4];
    float pdv[8];
    {
        const int* spp = span + ((size_t)(b * Ss + rbase + quad * 4)) * Ss
                              + cbase + l15;
        #pragma unroll
        for (int t = 0; t < 8; ++t) {
            pdv[t] = mask[b * Ss + cbase + t * 16 + l15];
            #pragma unroll
            for (int reg = 0; reg < 4; ++reg)
                spv[t][reg] = spp[(size_t)reg * Ss + t * 16];
        }
    }

    // ---- A frags (Q): rows rbase + l15
    const short* qp = qbf + (size_t)(b * Ss + rbase + l15) * Dd + quad * 8;
    short8 a0 = *(const short8*)(qp);
    short8 a1 = *(const short8*)(qp + 32);

    floatx4 acc[8];
    #pragma unroll
    for (int t = 0; t < 8; ++t) acc[t] = (floatx4){0.f, 0.f, 0.f, 0.f};

    // ---- B frags (K): cols cbase + t*16 + l15; two K-chunks.
    const short* kp = kbf + (size_t)(b * Ss + cbase + l15) * Dd + quad * 8;
    #pragma unroll
    for (int t = 0; t < 8; ++t) {
        short8 bv = *(const short8*)(kp + (size_t)t * 16 * Dd);
        acc[t] = __builtin_amdgcn_mfma_f32_16x16x32_bf16(a0, bv, acc[t], 0, 0, 0);
    }
    #pragma unroll
    for (int t = 0; t < 8; ++t) {
        short8 bv = *(const short8*)(kp + (size_t)t * 16 * Dd + 32);
        acc[t] = __builtin_amdgcn_mfma_f32_16x16x32_bf16(a1, bv, acc[t], 0, 0, 0);
    }

    // ---- Epilogue: transform dots -> yp in place, pack span bits.
    unsigned spb = 0;
    #pragma unroll
    for (int t = 0; t < 8; ++t) {
        const int n = cbase + t * 16 + l15;
        const float pd = pdv[t];
        #pragma unroll
        for (int reg = 0; reg < 4; ++reg) {
            const int m = rbase + quad * 4 + reg;
            const int sv = spv[t][reg];
            float logit = acc[t][reg] * pd - (1.0f - pd) * BIGF;
            if (n < m) logit -= BIGF;
            logit *= 0.125f;
            float ft = (float)sv;
            acc[t][reg] = (1.0f - 2.0f * ft) * logit;   // yp
            spb |= (unsigned)(sv != 0) << (t * 4 + reg);
        }
    }

    // ---- Pass 1: max (zero entry folded via init 0).
    float mxn[4] = {0.f, 0.f, 0.f, 0.f};
    float mxp[4] = {0.f, 0.f, 0.f, 0.f};
    #pragma unroll
    for (int t = 0; t < 8; ++t) {
        #pragma unroll
        for (int reg = 0; reg < 4; ++reg) {
            float ft = (float)((spb >> (t * 4 + reg)) & 1u);
            float yp = acc[t][reg];
            mxn[reg] = fmaxf(mxn[reg], yp - ft * BIGF);
            mxp[reg] = fmaxf(mxp[reg], yp - (1.0f - ft) * BIGF);
        }
    }
    #pragma unroll
    for (int off = 1; off < 16; off <<= 1) {
        #pragma unroll
        for (int reg = 0; reg < 4; ++reg) {
            mxn[reg] = fmaxf(mxn[reg], __shfl_xor(mxn[reg], off));
            mxp[reg] = fmaxf(mxp[reg], __shfl_xor(mxp[reg], off));
        }
    }
    if (l15 == 0) {
        #pragma unroll
        for (int reg = 0; reg < 4; ++reg) {
            part[0][cg][rh * 16 + quad * 4 + reg] = mxn[reg];
            part[1][cg][rh * 16 + quad * 4 + reg] = mxp[reg];
        }
    }
    __syncthreads();
    if (tid < 64) {
        int np = tid >> 5, r = tid & 31;
        float mv = fmaxf(fmaxf(part[np][0][r], part[np][1][r]),
                         fmaxf(part[np][2][r], part[np][3][r]));
        bred[np][r] = mv;
    }
    __syncthreads();

    // ---- Pass 2: sum of exp(v - max).
    float bmn[4], bmp[4];
    #pragma unroll
    for (int reg = 0; reg < 4; ++reg) {
        bmn[reg] = bred[0][rh * 16 + quad * 4 + reg];
        bmp[reg] = bred[1][rh * 16 + quad * 4 + reg];
    }
    float smn[4] = {0.f, 0.f, 0.f, 0.f};
    float smp[4] = {0.f, 0.f, 0.f, 0.f};
    #pragma unroll
    for (int t = 0; t < 8; ++t) {
        #pragma unroll
        for (int reg = 0; reg < 4; ++reg) {
            float ft = (float)((spb >> (t * 4 + reg)) & 1u);
            float yp = acc[t][reg];
            smn[reg] += __expf(yp - ft * BIGF - bmn[reg]);
            smp[reg] += __expf(yp - (1.0f - ft) * BIGF - bmp[reg]);
        }
    }
    #pragma unroll
    for (int off = 1; off < 16; off <<= 1) {
        #pragma unroll
        for (int reg = 0; reg < 4; ++reg) {
            smn[reg] += __shfl_xor(smn[reg], off);
            smp[reg] += __shfl_xor(smp[reg], off);
        }
    }
    if (l15 == 0) {
        #pragma unroll
        for (int reg = 0; reg < 4; ++reg) {
            part[0][cg][rh * 16 + quad * 4 + reg] = smn[reg];
            part[1][cg][rh * 16 + quad * 4 + reg] = smp[reg];
        }
    }
    __syncthreads();

    if (tid < 32) {
        int r = tid;
        float SN = __expf(-bred[0][r])
                 + part[0][0][r] + part[0][1][r] + part[0][2][r] + part[0][3][r];
        float SP = __expf(-bred[1][r])
                 + part[1][0][r] + part[1][1][r] + part[1][2][r] + part[1][3][r];
        float lse = (bred[0][r] + logf(SN)) + (bred[1][r] + logf(SP));
        rowsum[(size_t)(b * Ss + m0 + r)] = (double)lse;
    }
}

// ---------------------------------------------------------------------------
// Kernel 3: fp64 mean over 16384 row sums -> fp32 scalar.
// ---------------------------------------------------------------------------
__global__ __launch_bounds__(1024) void final_reduce_kernel(
    const double* __restrict__ rowsum, float* __restrict__ out)
{
    __shared__ double sh[1024];
    const int tid = threadIdx.x;
    double s = 0.0;
    #pragma unroll
    for (int i = 0; i < 16; ++i) s += rowsum[tid + i * 1024];
    sh[tid] = s;
    __syncthreads();
    for (int off = 512; off > 0; off >>= 1) {
        if (tid < off) sh[tid] += sh[tid + off];
        __syncthreads();
    }
    if (tid == 0) out[0] = (float)(sh[0] / (double)Mrows);
}

// ---------------------------------------------------------------------------
extern "C" void kernel_launch(void* const* d_in, const int* in_sizes, int n_in,
                              void* d_out, int out_size, void* d_ws, size_t ws_size,
                              hipStream_t stream)
{
    const float* hidden = (const float*)d_in[0];   // (B,S,H)
    const float* mask   = (const float*)d_in[1];   // (B,S)
    const int*   span   = (const int*)  d_in[2];   // (B,S,S)
    const float* w      = (const float*)d_in[3];   // (H, 2D)
    const float* bias   = (const float*)d_in[4];   // (2D,)
    float* out = (float*)d_out;

    // ws layout:
    //  [rowsum: 16384 f64           = 131072 B]
    //  [wfrag:  98304 bf16          = 196608 B]
    //  [rt:     16384 float2        = 131072 B]
    //  [qbf:    16384*64 bf16       = 2 MB]
    //  [kbf:    16384*64 bf16       = 2 MB]
    char* p = (char*)d_ws;
    double* rowsum = (double*)p;            p += 131072;
    short*  wfrag  = (short*)p;             p += 196608;
    float2* rt     = (float2*)p;            p += 131072;
    short*  qbf    = (short*)p;             p += (size_t)Mrows * Dd * 2;
    short*  kbf    = (short*)p;

    prep_kernel<<<Hh * ND / 256, 256, 0, stream>>>(w, wfrag, rt);
    proj_rope_kernel<<<Mrows / 32, 256, 0, stream>>>(hidden, wfrag, bias, rt, qbf, kbf);
    span_loss_kernel<<<Bb * 16, 512, 0, stream>>>(qbf, kbf, mask, span, rowsum);
    final_reduce_kernel<<<1, 1024, 0, stream>>>(rowsum, out);
}